// Round 4
// baseline (187.856 us; speedup 1.0000x reference)
//
#include <hip/hip_runtime.h>
#include <stdint.h>

#define N_BATCH 32
#define B_OBJ   36
#define D_DIM   2048
#define Q_DIM   1024

typedef __bf16 bf16x8 __attribute__((ext_vector_type(8)));
typedef float  f32x4  __attribute__((ext_vector_type(4)));

__device__ __forceinline__ uint16_t f2bf(float f) {
    uint32_t u = __builtin_bit_cast(uint32_t, f);
    uint32_t r = (u + 0x7FFFu + ((u >> 16) & 1u)) >> 16;   // RNE
    return (uint16_t)r;
}

__device__ __forceinline__ void gld_lds16(const void* g, void* l) {
    __builtin_amdgcn_global_load_lds(
        (const __attribute__((address_space(1))) uint32_t*)g,
        (__attribute__((address_space(3))) uint32_t*)l, 16, 0, 0);
}

// ---- transpose + fp32->bf16, 64x64 tiles, vectorized ----
__global__ __launch_bounds__(256) void transpose_all(
    const float* __restrict__ W1, const float* __restrict__ W2,
    const float* __restrict__ W3,
    uint16_t* __restrict__ W1t, uint16_t* __restrict__ W2t,
    uint16_t* __restrict__ W3t) {
    __shared__ float tile[64][65];
    int gy = blockIdx.y;
    const float* W; uint16_t* Wt; int K, k0;
    if (gy < 32)      { W = W1; Wt = W1t; K = 2048; k0 = gy * 64; }
    else if (gy < 64) { W = W2; Wt = W2t; K = 2048; k0 = (gy - 32) * 64; }
    else              { W = W3; Wt = W3t; K = 1024; k0 = (gy - 64) * 64; }
    int n0 = blockIdx.x * 64;
    int t = threadIdx.x;
    {
        int r = t >> 4, c = (t & 15) * 4;
#pragma unroll
        for (int p = 0; p < 4; ++p)
            *(float4*)&tile[r + p * 16][c] =
                *(const float4*)&W[(size_t)(k0 + r + p * 16) * 2048 + n0 + c];
    }
    __syncthreads();
    {
        int n = t >> 2, kb = (t & 3) * 16;
#pragma unroll
        for (int g4 = 0; g4 < 4; ++g4) {
            int k = kb + g4 * 4;
            ushort4 o;
            o.x = f2bf(tile[k][n]);     o.y = f2bf(tile[k + 1][n]);
            o.z = f2bf(tile[k + 2][n]); o.w = f2bf(tile[k + 3][n]);
            *(ushort4*)&Wt[(size_t)(n0 + n) * K + k0 + k] = o;
        }
    }
}

// ---- qe GEMM: qpart[z] = q @ W3 over K-chunk z (M=32, N=2048, split-K=4) ----
__global__ __launch_bounds__(256) void qk_gemm(
    const float* __restrict__ q,
    const uint16_t* __restrict__ W3t,
    float* __restrict__ qpart) {
    __shared__ __align__(16) uint16_t As[32][32];
    __shared__ __align__(16) uint16_t Bs[128][32];
    int t = threadIdx.x, lane = t & 63, wave = t >> 6;
    int l15 = lane & 15, quad = lane >> 4;
    int n0 = blockIdx.x * 128;
    int kbase = blockIdx.y * 256;
    f32x4 acc[2][2] = {};
    int ar = t >> 3, ac = (t & 7) * 4;
    int br = t >> 2, bk = (t & 3) * 8;

    for (int k0 = 0; k0 < 256; k0 += 32) {
        __syncthreads();
        float4 av = *(const float4*)&q[(size_t)ar * Q_DIM + kbase + k0 + ac];
        ushort4 a4;
        a4.x = f2bf(av.x); a4.y = f2bf(av.y); a4.z = f2bf(av.z); a4.w = f2bf(av.w);
        *(ushort4*)&As[ar][ac] = a4;
        *(uint4*)&Bs[br][bk]      = *(const uint4*)&W3t[(size_t)(n0 + br) * Q_DIM + kbase + k0 + bk];
        *(uint4*)&Bs[br + 64][bk] = *(const uint4*)&W3t[(size_t)(n0 + br + 64) * Q_DIM + kbase + k0 + bk];
        __syncthreads();
        bf16x8 af[2], bfr[2];
        af[0]  = *(const bf16x8*)&As[l15][quad * 8];
        af[1]  = *(const bf16x8*)&As[16 + l15][quad * 8];
        bfr[0] = *(const bf16x8*)&Bs[wave * 32 + l15][quad * 8];
        bfr[1] = *(const bf16x8*)&Bs[wave * 32 + 16 + l15][quad * 8];
#pragma unroll
        for (int i = 0; i < 2; ++i)
#pragma unroll
            for (int j = 0; j < 2; ++j)
                acc[i][j] = __builtin_amdgcn_mfma_f32_16x16x32_bf16(af[i], bfr[j], acc[i][j], 0, 0, 0);
    }
    float* dst = qpart + (size_t)blockIdx.y * 32 * D_DIM;
#pragma unroll
    for (int i = 0; i < 2; ++i)
#pragma unroll
        for (int j = 0; j < 2; ++j) {
            int n = n0 + wave * 32 + j * 16 + l15;
#pragma unroll
            for (int r = 0; r < 4; ++r)
                dst[(size_t)(i * 16 + quad * 4 + r) * D_DIM + n] = acc[i][j][r];
        }
}

// ---- fused: qe = relu(sum_z qpart + b3); u[n,i,:] = bf16(v[n,i,:]*qe) ----
__global__ __launch_bounds__(256) void qe_makeu(
    const float* __restrict__ qpart, const float* __restrict__ b3,
    const float* __restrict__ v, uint16_t* __restrict__ u) {
    int n = blockIdx.y;
    int c4 = blockIdx.x * 256 + threadIdx.x;     // float4 col, 512 per row
    const float4* p = (const float4*)qpart;
    size_t base = (size_t)n * 512 + c4;
    float4 s0 = p[base], s1 = p[16384 + base], s2 = p[32768 + base], s3 = p[49152 + base];
    float4 b = ((const float4*)b3)[c4];
    float4 qe;
    qe.x = fmaxf(s0.x + s1.x + s2.x + s3.x + b.x, 0.f);
    qe.y = fmaxf(s0.y + s1.y + s2.y + s3.y + b.y, 0.f);
    qe.z = fmaxf(s0.z + s1.z + s2.z + s3.z + b.z, 0.f);
    qe.w = fmaxf(s0.w + s1.w + s2.w + s3.w + b.w, 0.f);
    const float4* v4 = (const float4*)v + (size_t)n * B_OBJ * 512 + c4;
    ushort4* u4 = (ushort4*)u + (size_t)n * B_OBJ * 512 + c4;
#pragma unroll 4
    for (int i = 0; i < B_OBJ; ++i) {
        float4 vv = v4[(size_t)i * 512];
        ushort4 o;
        o.x = f2bf(vv.x * qe.x); o.y = f2bf(vv.y * qe.y);
        o.z = f2bf(vv.z * qe.z); o.w = f2bf(vv.w * qe.w);
        u4[(size_t)i * 512] = o;
    }
}

// ---- per-2-batch GEMM: tile M=80(72 real = 2 batches) x N=128, BK=128 ----
// mode 0: pairsum epilogue -> x (bf16). mode 1: relu(+bias) -> out (f32).
__global__ __launch_bounds__(256) void gemm_batch(
    const uint16_t* __restrict__ A,    // 1152 x 2048 bf16 (+8 pad rows readable)
    const uint16_t* __restrict__ Bt,   // 2048 x 2048 bf16 (n-major)
    const float* __restrict__ bias,
    void* __restrict__ Cv,
    int mode) {
    // staging: As[4][80][32] (20480 B) + Bs[4][128][32] (32768 B) = 53248 B
    // epilogue (mode 0): yt[72][132] f32 = 38016 B (reuses same LDS)
    __shared__ __align__(16) float smemf[13312];
    uint16_t* As = (uint16_t*)smemf;
    uint16_t* Bs = As + 10240;
    float* yt = smemf;

    int t = threadIdx.x, lane = t & 63, wave = t >> 6;
    int l15 = lane & 15, quad = lane >> 4;
    int bg = blockIdx.y;                 // batch-group: rows 72*bg .. +71
    int n0 = blockIdx.x * 128;
    const uint16_t* Ab = A + (size_t)bg * 72 * D_DIM;

    // 52 1-KiB staging regions: 0..19 = A (h=r/5,g=r%5), 20..51 = B
    const uint16_t* gp[13]; uint16_t* lp[13];
#pragma unroll
    for (int c = 0; c < 13; ++c) {
        int r = wave * 13 + c;
        int row16 = lane >> 2, kin = (lane & 3) * 8;
        if (r < 20) {
            int h = r / 5, g = r % 5;
            gp[c] = Ab + (size_t)(g * 16 + row16) * D_DIM + h * 32 + kin;
            lp[c] = As + h * 2560 + g * 512;
        } else {
            int rb = r - 20, h = rb >> 3, g = rb & 7;
            gp[c] = Bt + (size_t)(n0 + g * 16 + row16) * D_DIM + h * 32 + kin;
            lp[c] = Bs + h * 4096 + g * 512;
        }
    }

    f32x4 acc[5][2] = {};

    for (int k0 = 0; k0 < D_DIM; k0 += 128) {
        __syncthreads();
#pragma unroll
        for (int c = 0; c < 13; ++c) gld_lds16(gp[c] + k0, lp[c]);
        __syncthreads();
#pragma unroll
        for (int s = 0; s < 4; ++s) {
            bf16x8 af[5], bfr[2];
#pragma unroll
            for (int i = 0; i < 5; ++i)
                af[i] = *(const bf16x8*)(As + s * 2560 + (i * 16 + l15) * 32 + quad * 8);
#pragma unroll
            for (int j = 0; j < 2; ++j)
                bfr[j] = *(const bf16x8*)(Bs + s * 4096 + (wave * 32 + j * 16 + l15) * 32 + quad * 8);
#pragma unroll
            for (int i = 0; i < 5; ++i)
#pragma unroll
                for (int j = 0; j < 2; ++j)
                    acc[i][j] = __builtin_amdgcn_mfma_f32_16x16x32_bf16(af[i], bfr[j], acc[i][j], 0, 0, 0);
        }
    }

    if (mode == 0) {
        uint16_t* X = (uint16_t*)Cv;
        __syncthreads();
#pragma unroll
        for (int i = 0; i < 5; ++i)
#pragma unroll
            for (int r = 0; r < 4; ++r) {
                int row = i * 16 + quad * 4 + r;
                if (row < 72)
#pragma unroll
                    for (int j = 0; j < 2; ++j)
                        yt[row * 132 + wave * 32 + j * 16 + l15] = acc[i][j][r];
            }
        __syncthreads();
        int col = t & 127, half = t >> 7;       // half = batch within group
        float b = bias[n0 + col];
        float z[36];
#pragma unroll
        for (int j2 = 0; j2 < 36; ++j2) z[j2] = yt[(half * 36 + j2) * 132 + col];
        int batch = bg * 2 + half;
#pragma unroll
        for (int i2 = 0; i2 < 36; ++i2) {
            float zi = z[i2] + b;
            float s = 0.f;
#pragma unroll
            for (int j2 = 0; j2 < 36; ++j2) s += fmaxf(zi + z[j2], 0.f);
            X[(size_t)(batch * 36 + i2) * D_DIM + n0 + col] = f2bf(s);
        }
    } else {
        float* O = (float*)Cv;
#pragma unroll
        for (int i = 0; i < 5; ++i)
#pragma unroll
            for (int r = 0; r < 4; ++r) {
                int row = i * 16 + quad * 4 + r;
                if (row < 72)
#pragma unroll
                    for (int j = 0; j < 2; ++j) {
                        int cc = n0 + wave * 32 + j * 16 + l15;
                        O[(size_t)(bg * 72 + row) * D_DIM + cc] =
                            fmaxf(acc[i][j][r] + bias[cc], 0.f);
                    }
            }
    }
}

extern "C" void kernel_launch(void* const* d_in, const int* in_sizes, int n_in,
                              void* d_out, int out_size, void* d_ws, size_t ws_size,
                              hipStream_t stream) {
    const float* v  = (const float*)d_in[0];
    const float* q  = (const float*)d_in[1];
    const float* W1 = (const float*)d_in[2];
    const float* b1 = (const float*)d_in[3];
    const float* W2 = (const float*)d_in[4];
    const float* b2 = (const float*)d_in[5];
    const float* W3 = (const float*)d_in[6];
    const float* b3 = (const float*)d_in[7];
    float* out = (float*)d_out;

    char* ws = (char*)d_ws;
    uint16_t* W1t   = (uint16_t*)(ws + 0);           // 8 MiB
    uint16_t* W2t   = (uint16_t*)(ws + 8388608);     // 8 MiB
    uint16_t* W3t   = (uint16_t*)(ws + 16777216);    // 4 MiB, dead after qk_gemm
    uint16_t* u     = (uint16_t*)(ws + 16777216);    // 4.5 MiB (overlays dead W3t)
    float*    qpart = (float*)   (ws + 21495808);    // 1 MiB (also pads A-row over-reads)
    uint16_t* x     = (uint16_t*)(ws + 22806528);    // 4.5 MiB (+32 KiB over-read pad ok)

    transpose_all<<<dim3(32, 80), 256, 0, stream>>>(W1, W2, W3, W1t, W2t, W3t);

    qk_gemm<<<dim3(16, 4), 256, 0, stream>>>(q, W3t, qpart);

    qe_makeu<<<dim3(2, N_BATCH), 256, 0, stream>>>(qpart, b3, v, u);

    // GEMM1 + fused pairsum -> x (bf16)
    gemm_batch<<<dim3(16, 16), 256, 0, stream>>>(u, W1t, b1, x, 0);

    // GEMM2 + bias + relu -> out (f32)
    gemm_batch<<<dim3(16, 16), 256, 0, stream>>>(x, W2t, b2, out, 1);
}

// Round 5
// 185.850 us; speedup vs baseline: 1.0108x; 1.0108x over previous
//
#include <hip/hip_runtime.h>
#include <stdint.h>

#define N_BATCH 32
#define B_OBJ   36
#define D_DIM   2048
#define Q_DIM   1024

typedef __bf16 bf16x8 __attribute__((ext_vector_type(8)));
typedef float  f32x4  __attribute__((ext_vector_type(4)));

__device__ __forceinline__ uint16_t f2bf(float f) {
    uint32_t u = __builtin_bit_cast(uint32_t, f);
    uint32_t r = (u + 0x7FFFu + ((u >> 16) & 1u)) >> 16;   // RNE
    return (uint16_t)r;
}

__device__ __forceinline__ void gld_lds16(const void* g, void* l) {
    __builtin_amdgcn_global_load_lds(
        (const __attribute__((address_space(1))) uint32_t*)g,
        (__attribute__((address_space(3))) uint32_t*)l, 16, 0, 0);
}

// ---- transpose + fp32->bf16 for W1, W2 (2048x2048 each) ----
__global__ __launch_bounds__(256) void transpose_all(
    const float* __restrict__ W1, const float* __restrict__ W2,
    uint16_t* __restrict__ W1t, uint16_t* __restrict__ W2t) {
    __shared__ float tile[64][65];
    int gy = blockIdx.y;
    const float* W; uint16_t* Wt; int k0;
    if (gy < 32) { W = W1; Wt = W1t; k0 = gy * 64; }
    else         { W = W2; Wt = W2t; k0 = (gy - 32) * 64; }
    int n0 = blockIdx.x * 64;
    int t = threadIdx.x;
    {
        int r = t >> 4, c = (t & 15) * 4;
#pragma unroll
        for (int p = 0; p < 4; ++p)
            *(float4*)&tile[r + p * 16][c] =
                *(const float4*)&W[(size_t)(k0 + r + p * 16) * 2048 + n0 + c];
    }
    __syncthreads();
    {
        int n = t >> 2, kb = (t & 3) * 16;
#pragma unroll
        for (int g4 = 0; g4 < 4; ++g4) {
            int k = kb + g4 * 4;
            ushort4 o;
            o.x = f2bf(tile[k][n]);     o.y = f2bf(tile[k + 1][n]);
            o.z = f2bf(tile[k + 2][n]); o.w = f2bf(tile[k + 3][n]);
            *(ushort4*)&Wt[(size_t)(n0 + n) * 2048 + k0 + k] = o;
        }
    }
}

// ---- q-path fp32: qpart[kz][n][e] = sum over k-chunk of q[n,k]*W3[k,e] ----
// grid (32 e-tiles of 64, 8 k-chunks of 128)
__global__ __launch_bounds__(256) void qe_f32(
    const float* __restrict__ q, const float* __restrict__ W3,
    float* __restrict__ qpart) {
    __shared__ float qs[128][32];     // [k][n]
    int t = threadIdx.x;
    int e0 = blockIdx.x * 64;
    int kbase = blockIdx.y * 128;
    {
        int nn = t >> 3, kg = (t & 7) * 16;
#pragma unroll
        for (int p = 0; p < 4; ++p) {
            float4 f = *(const float4*)&q[(size_t)nn * Q_DIM + kbase + kg + p * 4];
            qs[kg + p * 4 + 0][nn] = f.x; qs[kg + p * 4 + 1][nn] = f.y;
            qs[kg + p * 4 + 2][nn] = f.z; qs[kg + p * 4 + 3][nn] = f.w;
        }
    }
    __syncthreads();
    int n = t >> 3, e8 = (t & 7) * 8;
    float acc[8] = {};
#pragma unroll 4
    for (int k = 0; k < 128; ++k) {
        float qv = qs[k][n];
        float4 wa = *(const float4*)&W3[(size_t)(kbase + k) * D_DIM + e0 + e8];
        float4 wb = *(const float4*)&W3[(size_t)(kbase + k) * D_DIM + e0 + e8 + 4];
        acc[0] += qv * wa.x; acc[1] += qv * wa.y; acc[2] += qv * wa.z; acc[3] += qv * wa.w;
        acc[4] += qv * wb.x; acc[5] += qv * wb.y; acc[6] += qv * wb.z; acc[7] += qv * wb.w;
    }
    float* dst = qpart + (size_t)blockIdx.y * 32 * D_DIM + (size_t)n * D_DIM + e0 + e8;
    *(float4*)dst = *(float4*)&acc[0];
    *(float4*)(dst + 4) = *(float4*)&acc[4];
}

// ---- fused: qe = relu(sum_z qpart + b3); u[n,i,:] = bf16(v[n,i,:]*qe) ----
__global__ __launch_bounds__(256) void qe_makeu(
    const float* __restrict__ qpart, const float* __restrict__ b3,
    const float* __restrict__ v, uint16_t* __restrict__ u) {
    int n = blockIdx.y;
    int c4 = blockIdx.x * 256 + threadIdx.x;     // float4 col, 512 per row
    const float4* p = (const float4*)qpart;
    size_t base = (size_t)n * 512 + c4;
    float4 s = p[base];
#pragma unroll
    for (int z = 1; z < 8; ++z) {
        float4 sz = p[(size_t)z * 16384 + base];
        s.x += sz.x; s.y += sz.y; s.z += sz.z; s.w += sz.w;
    }
    float4 b = ((const float4*)b3)[c4];
    float4 qe;
    qe.x = fmaxf(s.x + b.x, 0.f); qe.y = fmaxf(s.y + b.y, 0.f);
    qe.z = fmaxf(s.z + b.z, 0.f); qe.w = fmaxf(s.w + b.w, 0.f);
    const float4* v4 = (const float4*)v + (size_t)n * B_OBJ * 512 + c4;
    ushort4* u4 = (ushort4*)u + (size_t)n * B_OBJ * 512 + c4;
#pragma unroll 4
    for (int i = 0; i < B_OBJ; ++i) {
        float4 vv = v4[(size_t)i * 512];
        ushort4 o;
        o.x = f2bf(vv.x * qe.x); o.y = f2bf(vv.y * qe.y);
        o.z = f2bf(vv.z * qe.z); o.w = f2bf(vv.w * qe.w);
        u4[(size_t)i * 512] = o;
    }
}

// ---- split-K GEMM partial: Yp[kz] += A(128x1024 slice) @ Bt(64x1024 slice)^T
// tile 128x64, BK=64, double-buffered LDS, ONE barrier per iter.
__global__ __launch_bounds__(256) void gemm_ks(
    const uint16_t* __restrict__ A,    // 1152 x 2048 bf16
    const uint16_t* __restrict__ Bt,   // 2048 x 2048 bf16 (n-major)
    float* __restrict__ Yp) {          // 2 x 1152 x 2048 f32 partials
    // flat LDS: As buf0 [0,8192) buf1 [8192,16384); Bs buf0 [16384,20480) buf1 [20480,24576)
    __shared__ __align__(16) uint16_t sm[24576];   // 48 KiB
    int t = threadIdx.x, lane = t & 63, wave = t >> 6;
    int l15 = lane & 15, quad = lane >> 4;
    int wr = wave >> 1, wc = wave & 1;
    int n0 = blockIdx.x * 64, m0 = blockIdx.y * 128, kz = blockIdx.z;
    const uint16_t* Ab = A  + (size_t)m0 * D_DIM + kz * 1024;
    const uint16_t* Bb = Bt + (size_t)n0 * D_DIM + kz * 1024;

    // 24 1-KiB staging regions: 0..15 = A [h=r>>3][g=r&7], 16..23 = B
    const uint16_t* gp[6]; uint16_t* lp[6]; int ofs[6];
#pragma unroll
    for (int c = 0; c < 6; ++c) {
        int r = wave + 4 * c;
        int row16 = lane >> 2, kin = (lane & 3) * 8;
        if (r < 16) {
            int h = r >> 3, g = r & 7;
            gp[c] = Ab + (size_t)(g * 16 + row16) * D_DIM + h * 32 + kin;
            lp[c] = sm + h * 4096 + g * 512;
            ofs[c] = 8192;
        } else {
            int rb = r - 16, h = rb >> 2, g = rb & 3;
            gp[c] = Bb + (size_t)(g * 16 + row16) * D_DIM + h * 32 + kin;
            lp[c] = sm + 16384 + h * 2048 + g * 512;
            ofs[c] = 4096;
        }
    }

    f32x4 acc[4][2] = {};

    // prologue: fill buffer 0
#pragma unroll
    for (int c = 0; c < 6; ++c) gld_lds16(gp[c], lp[c]);

    for (int it = 0; it < 16; ++it) {
        int buf = it & 1;
        __syncthreads();            // drains buf's loads (issued last iter / prologue)
        if (it < 15) {              // prefetch next buffer — overlaps this iter's compute
            int nxt = buf ^ 1;
#pragma unroll
            for (int c = 0; c < 6; ++c)
                gld_lds16(gp[c] + (it + 1) * 64, lp[c] + nxt * ofs[c]);
        }
#pragma unroll
        for (int s = 0; s < 2; ++s) {
            bf16x8 af[4], bfr[2];
#pragma unroll
            for (int i = 0; i < 4; ++i)
                af[i] = *(const bf16x8*)(sm + buf * 8192 + s * 4096 +
                                         (wr * 64 + i * 16 + l15) * 32 + quad * 8);
#pragma unroll
            for (int j = 0; j < 2; ++j)
                bfr[j] = *(const bf16x8*)(sm + 16384 + buf * 4096 + s * 2048 +
                                          (wc * 32 + j * 16 + l15) * 32 + quad * 8);
#pragma unroll
            for (int i = 0; i < 4; ++i)
#pragma unroll
                for (int j = 0; j < 2; ++j)
                    acc[i][j] = __builtin_amdgcn_mfma_f32_16x16x32_bf16(af[i], bfr[j], acc[i][j], 0, 0, 0);
        }
    }

    float* Y = Yp + (size_t)kz * 1152 * D_DIM;
#pragma unroll
    for (int i = 0; i < 4; ++i)
#pragma unroll
        for (int j = 0; j < 2; ++j) {
            int col = n0 + wc * 32 + j * 16 + l15;
#pragma unroll
            for (int r = 0; r < 4; ++r)
                Y[(size_t)(m0 + wr * 64 + i * 16 + quad * 4 + r) * D_DIM + col] = acc[i][j][r];
        }
}

// ---- reduce partials + pairsum: x = bf16( sum_j relu(y_i + y_j + b1) ) ----
__global__ __launch_bounds__(256) void pairsum_red(
    const float* __restrict__ Yp, const float* __restrict__ b1,
    uint16_t* __restrict__ X) {
    int n = blockIdx.y;
    int d = blockIdx.x * 256 + threadIdx.x;
    const float* y0 = Yp + (size_t)(n * B_OBJ) * D_DIM + d;
    const float* y1 = y0 + (size_t)1152 * D_DIM;
    float z[B_OBJ];
#pragma unroll
    for (int j = 0; j < B_OBJ; ++j)
        z[j] = y0[(size_t)j * D_DIM] + y1[(size_t)j * D_DIM];
    float b = b1[d];
    uint16_t* xb = X + (size_t)(n * B_OBJ) * D_DIM + d;
#pragma unroll
    for (int i = 0; i < B_OBJ; ++i) {
        float zi = z[i] + b;
        float s = 0.f;
#pragma unroll
        for (int j = 0; j < B_OBJ; ++j) s += fmaxf(zi + z[j], 0.f);
        xb[(size_t)i * D_DIM] = f2bf(s);
    }
}

// ---- reduce partials + bias + relu -> out f32 ----
__global__ __launch_bounds__(256) void reduce_out(
    const float* __restrict__ Op, const float* __restrict__ b2,
    float* __restrict__ out) {
    int i = blockIdx.x * 256 + threadIdx.x;      // float4 id, 589824 total
    const float4* p = (const float4*)Op;
    float4 a = p[i], b = p[589824 + i];
    float4 bb = ((const float4*)b2)[i & 511];
    float4 o;
    o.x = fmaxf(a.x + b.x + bb.x, 0.f);
    o.y = fmaxf(a.y + b.y + bb.y, 0.f);
    o.z = fmaxf(a.z + b.z + bb.z, 0.f);
    o.w = fmaxf(a.w + b.w + bb.w, 0.f);
    ((float4*)out)[i] = o;
}

extern "C" void kernel_launch(void* const* d_in, const int* in_sizes, int n_in,
                              void* d_out, int out_size, void* d_ws, size_t ws_size,
                              hipStream_t stream) {
    const float* v  = (const float*)d_in[0];
    const float* q  = (const float*)d_in[1];
    const float* W1 = (const float*)d_in[2];
    const float* b1 = (const float*)d_in[3];
    const float* W2 = (const float*)d_in[4];
    const float* b2 = (const float*)d_in[5];
    const float* W3 = (const float*)d_in[6];
    const float* b3 = (const float*)d_in[7];
    float* out = (float*)d_out;

    char* ws = (char*)d_ws;
    uint16_t* W1t   = (uint16_t*)(ws + 0);           //  8 MiB
    uint16_t* W2t   = (uint16_t*)(ws + 8388608);     //  8 MiB
    uint16_t* u     = (uint16_t*)(ws + 16777216);    //  4.5 MiB
    float*    qpart = (float*)   (ws + 21495808);    //  2 MiB (8x32x2048)
    uint16_t* x     = (uint16_t*)(ws + 23592960);    //  4.5 MiB
    float*    Yp    = (float*)   (ws + 28311552);    // 18 MiB (2 partials)
    float*    Op    = Yp;                            // reuses Yp (dead after pairsum_red)

    transpose_all<<<dim3(32, 64), 256, 0, stream>>>(W1, W2, W1t, W2t);

    qe_f32<<<dim3(32, 8), 256, 0, stream>>>(q, W3, qpart);
    qe_makeu<<<dim3(2, N_BATCH), 256, 0, stream>>>(qpart, b3, v, u);

    gemm_ks<<<dim3(32, 9, 2), 256, 0, stream>>>(u, W1t, Yp);
    pairsum_red<<<dim3(8, N_BATCH), 256, 0, stream>>>(Yp, b1, x);

    gemm_ks<<<dim3(32, 9, 2), 256, 0, stream>>>(x, W2t, Op);
    reduce_out<<<2304, 256, 0, stream>>>(Op, b2, out);
}